// Round 3
// baseline (344.682 us; speedup 1.0000x reference)
//
#include <hip/hip_runtime.h>
#include <math.h>

#define NUM_JOINTS 21
#define BATCH 64
#define BJ (BATCH * NUM_JOINTS)   // 1344
#define IMG 256
#define IMG_PIX (IMG * IMG)       // 65536
#define F4_PER_IMG (IMG_PIX / 4)  // 16384 (power of 2)

typedef float v4f __attribute__((ext_vector_type(4)));

// ---------------------------------------------------------------------------
// Kernel A: compute the 1344 seed pixels (fisheye projection), store to ws.
// Mirrors the reference fp32 pipeline:
//   theta = atan2(sqrt(x*x+y*y), z); phi = atan2(y, x)
//   r = (128*theta) / float32(pi/2)
//   fish = rint(128 + r*cos/sin(phi)); clip to [0,255]
// rintf = round-half-even, matching jnp.round.
// ---------------------------------------------------------------------------
__global__ void seed_kernel(const float* __restrict__ joint,
                            int2* __restrict__ seeds) {
    int i = blockIdx.x * blockDim.x + threadIdx.x;
    if (i >= BJ) return;
    float x = joint[i * 3 + 0];
    float y = joint[i * 3 + 1];
    float z = joint[i * 3 + 2];
    float theta = atan2f(sqrtf(x * x + y * y), z);
    float phi   = atan2f(y, x);
    float r = (128.0f * theta) / 1.5707964f;   // fp32(pi/2)
    float fx = rintf(128.0f + r * cosf(phi));
    float fy = rintf(128.0f + r * sinf(phi));
    int sx = (int)fx;
    int sy = (int)fy;
    sx = min(max(sx, 0), IMG - 1);
    sy = min(max(sy, 0), IMG - 1);
    seeds[i] = make_int2(sx, sy);
}

// ---------------------------------------------------------------------------
// Kernel B: write the full 352 MB output, grid-strided (Guideline 11:
// memory-bound -> ~2048 blocks, stride the rest). Each iteration stores one
// coalesced nontemporal float4. Value is nonzero only inside the 11x11
// window centered on the seed:
//   out = exp(-(dy*dy)/12.5) * exp(-(dx*dx)/12.5)   (== outer(g1,g1), peak 1)
// The reference's /sum-then-/max normalization cancels (center tap = 1).
// ---------------------------------------------------------------------------
__global__ void __launch_bounds__(256)
fill_kernel(const int2* __restrict__ seeds, float* __restrict__ out) {
    const unsigned total = BJ * F4_PER_IMG;              // 22,020,096 float4s
    const unsigned stride = gridDim.x * blockDim.x;
    for (unsigned idx = blockIdx.x * blockDim.x + threadIdx.x;
         idx < total; idx += stride) {
        unsigned img = idx >> 14;            // (b*21 + j)
        unsigned p   = (idx & (F4_PER_IMG - 1)) << 2;  // pixel index in image
        int h = p >> 8;                      // row (y)
        int w = p & 255;                     // col (x) of first of 4 pixels

        int2 s = seeds[img];                 // tiny, L1/L2-hot
        int dy = h - s.y;

        v4f v = (v4f)0.0f;
        if (dy >= -5 && dy <= 5) {
            int dx0 = w - s.x;
            if (dx0 <= 5 && dx0 >= -8) {     // any of the 4 lanes in window
                float gy = expf(-(float)(dy * dy) / 12.5f);
                #pragma unroll
                for (int i = 0; i < 4; ++i) {
                    int dx = dx0 + i;
                    if (dx >= -5 && dx <= 5) {
                        v[i] = gy * expf(-(float)(dx * dx) / 12.5f);
                    }
                }
            }
        }

        v4f* dst = (v4f*)(out + (size_t)idx * 4);
        __builtin_nontemporal_store(v, dst);
    }
}

extern "C" void kernel_launch(void* const* d_in, const int* in_sizes, int n_in,
                              void* d_out, int out_size, void* d_ws, size_t ws_size,
                              hipStream_t stream) {
    const float* joint = (const float*)d_in[0];
    float* out = (float*)d_out;
    int2* seeds = (int2*)d_ws;    // 1344 * 8 B = 10.5 KB of scratch

    seed_kernel<<<(BJ + 255) / 256, 256, 0, stream>>>(joint, seeds);

    // 2048 blocks x 256 threads, ~42 float4 stores per thread
    fill_kernel<<<2048, 256, 0, stream>>>(seeds, out);
}

// Round 4
// 342.474 us; speedup vs baseline: 1.0064x; 1.0064x over previous
//
#include <hip/hip_runtime.h>
#include <math.h>

#define NUM_JOINTS 21
#define BATCH 64
#define BJ (BATCH * NUM_JOINTS)   // 1344
#define IMG 256
#define IMG_PIX (IMG * IMG)       // 65536

typedef float v4f __attribute__((ext_vector_type(4)));

// ---------------------------------------------------------------------------
// Kernel A: compute the 1344 seed pixels (fisheye projection) into ws.
// Bit-exact vs reference (round 3: absmax 0.0).
// ---------------------------------------------------------------------------
__global__ void seed_kernel(const float* __restrict__ joint,
                            int2* __restrict__ seeds) {
    int i = blockIdx.x * blockDim.x + threadIdx.x;
    if (i >= BJ) return;
    float x = joint[i * 3 + 0];
    float y = joint[i * 3 + 1];
    float z = joint[i * 3 + 2];
    float theta = atan2f(sqrtf(x * x + y * y), z);
    float phi   = atan2f(y, x);
    float r = (128.0f * theta) / 1.5707964f;   // fp32(pi/2)
    float fx = rintf(128.0f + r * cosf(phi));  // round-half-even == jnp.round
    float fy = rintf(128.0f + r * sinf(phi));
    int sx = (int)fx;
    int sy = (int)fy;
    sx = min(max(sx, 0), IMG - 1);
    sy = min(max(sy, 0), IMG - 1);
    seeds[i] = make_int2(sx, sy);
}

// ---------------------------------------------------------------------------
// Kernel B: write ONLY the 1344 11x11 Gaussian patches on top of the
// memset-zeroed output. Each patch row is covered by 4 aligned float4
// stores (extra lanes write zeros over zeros — harmless). One wave/patch:
// thread t<44 -> (row r = t>>2, quad q = t&3).
//   val = exp(-(dy*dy)/12.5) * exp(-(dx*dx)/12.5)   (== outer(g1,g1), peak 1)
// ---------------------------------------------------------------------------
__global__ void __launch_bounds__(64)
patch_kernel(const int2* __restrict__ seeds, float* __restrict__ out) {
    int img = blockIdx.x;
    int t = threadIdx.x;
    if (t >= 44) return;
    int2 s = seeds[img];
    int r = t >> 2;                 // 0..10
    int q = t & 3;                  // 0..3
    int y = s.y - 5 + r;
    if (y < 0 || y > IMG - 1) return;   // SAME padding: clipped rows drop
    int dyy = r - 5;
    float gy = expf(-(float)(dyy * dyy) / 12.5f);

    int c0 = (s.x - 5) & ~3;        // aligned base col (floor, works for <0)
    int cq = c0 + 4 * q;            // this quad's first col
    float vals[4];
    #pragma unroll
    for (int i = 0; i < 4; ++i) {
        int dx = cq + i - s.x;
        vals[i] = (dx >= -5 && dx <= 5)
                    ? gy * expf(-(float)(dx * dx) / 12.5f) : 0.0f;
    }
    float* row = out + (size_t)img * IMG_PIX + (size_t)y * IMG;
    if (cq >= 0 && cq + 3 <= IMG - 1) {
        v4f v = {vals[0], vals[1], vals[2], vals[3]};
        *(v4f*)(row + cq) = v;      // aligned 16B store
    } else {
        #pragma unroll
        for (int i = 0; i < 4; ++i) {   // image border: scalar, in-bounds only
            int c = cq + i;
            if (c >= 0 && c <= IMG - 1 && vals[i] != 0.0f) row[c] = vals[i];
        }
    }
}

extern "C" void kernel_launch(void* const* d_in, const int* in_sizes, int n_in,
                              void* d_out, int out_size, void* d_ws, size_t ws_size,
                              hipStream_t stream) {
    const float* joint = (const float*)d_in[0];
    float* out = (float*)d_out;
    int2* seeds = (int2*)d_ws;    // 1344 * 8 B = 10.5 KB of scratch

    // Bulk zero: AMD's fill path, measured at 6.27 TB/s on this machine.
    hipMemsetAsync(d_out, 0, (size_t)out_size * sizeof(float), stream);

    seed_kernel<<<(BJ + 255) / 256, 256, 0, stream>>>(joint, seeds);

    // 1344 patches, one wave each (~650 KB of aligned stores total).
    patch_kernel<<<BJ, 64, 0, stream>>>(seeds, out);
}